// Round 5
// baseline (531.114 us; speedup 1.0000x reference)
//
#include <hip/hip_runtime.h>
#include <hip/hip_fp16.h>

#define TT 100
#define BB 4096
#define GS 488   // floats per batch blob; 488 % 32 == 8 -> bank stagger

// per-batch float layout:
//   V   [0,144)     12x12 value matrix (row-addressed, NOT symmetrized)
//   Fl  [144,384)   12 rows x stride 20
//   Qxu [384,432)   Qxu[r*12+i] = Q[i][12+r]
//   Quu [432,448)   col-major 4x4
//   vv  [448,460)   v
//   tb  [460,472)   ft (backward only)

// wave-internal LDS fence: batch lives in one wave; no s_barrier needed.
#define FENCE() asm volatile("s_waitcnt lgkmcnt(0)" ::: "memory")

template<int KMODE>
__device__ __forceinline__ void storeK(void* wsv, size_t of, int l, float X0,float X1,float X2,float X3){
  if (KMODE==0){
    float* wsb=(float*)wsv + of*52;
    if (l<12)       ((float4*)wsb)[l]  = make_float4(X0,X1,X2,X3);
    else if (l==12) ((float4*)wsb)[12] = make_float4(X0,X1,X2,X3);
  } else {
    __half* wsb=(__half*)wsv + of*52;
    if (l<12){
      wsb[l*4+0]=__float2half(X0); wsb[l*4+1]=__float2half(X1);
      wsb[l*4+2]=__float2half(X2); wsb[l*4+3]=__float2half(X3);
    } else if (l==12){
      wsb[48]=__float2half(X0); wsb[49]=__float2half(X1);
      wsb[50]=__float2half(X2); wsb[51]=__float2half(X3);
    }
  }
}
template<int KMODE>
__device__ __forceinline__ float4 loadKcol(const void* wsv, size_t of, int l){
  if (KMODE==0) return ((const float4*)((const float*)wsv + of*52))[l];
  const __half* p=(const __half*)wsv + of*52 + l*4;
  return make_float4(__half2float(p[0]),__half2float(p[1]),__half2float(p[2]),__half2float(p[3]));
}
template<int KMODE>
__device__ __forceinline__ float loadkk(const void* wsv, size_t of, int r){
  if (KMODE==0) return ((const float*)wsv)[of*52+48+r];
  return __half2float(((const __half*)wsv)[of*52+48+r]);
}

template<int KMODE>
__global__ __launch_bounds__(256)
void lqr_fused(const float* __restrict__ xinit,
               const float* __restrict__ Cg,
               const float* __restrict__ cg,
               const float* __restrict__ Fg,
               const float* __restrict__ fg,
               float* __restrict__ out,
               void* __restrict__ wsv)
{
  __shared__ float smem[GS*8];
  const int tid  = threadIdx.x;
  const int gi   = tid >> 5;        // batch group in block (0..7)
  const int lane = tid & 63;
  const int l    = tid & 15;        // column
  const int h    = (tid >> 4) & 1;  // half (s/i ranges [6h,6h+6), C rows [8h,8h+8))
  const int b    = blockIdx.x*8 + gi;
  const int gb32 = lane & ~31;      // batch base lane within wave

  float* __restrict__ V   = smem + gi*GS;
  float* __restrict__ Fl  = V + 144;
  float* __restrict__ Qxu = V + 384;
  float* __restrict__ Quu = V + 432;
  float* __restrict__ vv  = V + 448;
  float* __restrict__ tb  = V + 460;

  // ================= backward Riccati =================
  float4 sCa,sCb; float sc_;
  float4 sFa=make_float4(0,0,0,0),sFb=sFa; float sf_=0.f;
  {
    const size_t of = ((size_t)(TT-1)*BB + b);
    const float4* pc = (const float4*)(Cg + of*256 + l*16);
    sCa=pc[2*h]; sCb=pc[2*h+1];      // C col l, rows [8h,8h+8)
    sc_ = cg[of*16 + l];
  }

  for (int tt=TT-1; tt>=0; --tt){
    const bool hasF = (tt < TT-1);
    float4 Ca=sCa,Cb=sCb; float rc=sc_;
    float4 Fa=sFa,Fb=sFb; float rf=sf_;

    if (hasF && l<12){
      float4* q=(float4*)(Fl + l*20);
      q[2*h]=Fa; q[2*h+1]=Fb;        // h0: cols 0-7, h1: cols 8-15 of row l
      if (h==0) tb[l]=rf;
    }
    FENCE(); // B1: Fl/tb staged; prev-iter V/vv writes visible

    if (tt>0){
      const size_t of = ((size_t)(tt-1)*BB + b);
      const float4* pc=(const float4*)(Cg + of*256 + l*16);
      sCa=pc[2*h]; sCb=pc[2*h+1];
      sc_=cg[of*16+l];
      if (l<12){
        const float4* pf=(const float4*)(Fg + of*192 + l*16);
        sFa=pf[2*h]; sFb=pf[2*h+1];
        if (h==0) sf_=fg[of*12+l];
      }
    }

    // partial Q column (C added on owning half's rows)
    const float R0=Ca.x,R1=Ca.y,R2=Ca.z,R3=Ca.w,R4=Cb.x,R5=Cb.y,R6=Cb.z,R7=Cb.w;
    float Qp[16];
    Qp[0]=h?0.f:R0; Qp[1]=h?0.f:R1; Qp[2]=h?0.f:R2; Qp[3]=h?0.f:R3;
    Qp[4]=h?0.f:R4; Qp[5]=h?0.f:R5; Qp[6]=h?0.f:R6; Qp[7]=h?0.f:R7;
    Qp[8]=h?R0:0.f; Qp[9]=h?R1:0.f; Qp[10]=h?R2:0.f; Qp[11]=h?R3:0.f;
    Qp[12]=h?R4:0.f; Qp[13]=h?R5:0.f; Qp[14]=h?R6:0.f; Qp[15]=h?R7:0.f;
    float qvp = h? 0.f : rc;

    if (hasF){
      float FtL[6], FtH[6];
      #pragma unroll
      for (int k2=0;k2<6;k2++){ FtL[k2]=Fl[k2*20+l]; FtH[k2]=Fl[(6+k2)*20+l]; }
      const int s0=6*h;
      float Wl[6];
      #pragma unroll
      for (int k2=0;k2<6;k2++){
        const float4* vr=(const float4*)(V+(s0+k2)*12);
        float4 v0=vr[0],v1=vr[1],v2=vr[2];
        Wl[k2]= v0.x*FtL[0]+v0.y*FtL[1]+v0.z*FtL[2]+v0.w*FtL[3]
              + v1.x*FtL[4]+v1.y*FtL[5]+v1.z*FtH[0]+v1.w*FtH[1]
              + v2.x*FtH[2]+v2.y*FtH[3]+v2.z*FtH[4]+v2.w*FtH[5];
      }
      #pragma unroll
      for (int k2=0;k2<6;k2++){
        const float4* fr=(const float4*)(Fl + (s0+k2)*20);
        float4 f0=fr[0],f1=fr[1],f2=fr[2],f3=fr[3];
        float w=Wl[k2];
        Qp[0]+=f0.x*w;  Qp[1]+=f0.y*w;  Qp[2]+=f0.z*w;  Qp[3]+=f0.w*w;
        Qp[4]+=f1.x*w;  Qp[5]+=f1.y*w;  Qp[6]+=f1.z*w;  Qp[7]+=f1.w*w;
        Qp[8]+=f2.x*w;  Qp[9]+=f2.y*w;  Qp[10]+=f2.z*w; Qp[11]+=f2.w*w;
        Qp[12]+=f3.x*w; Qp[13]+=f3.y*w; Qp[14]+=f3.z*w; Qp[15]+=f3.w*w;
      }
      #pragma unroll
      for (int k2=0;k2<6;k2++){
        qvp += Wl[k2]*tb[s0+k2];
        const float ftk = h? FtH[k2] : FtL[k2];
        qvp += ftk * vv[s0+k2];
      }
    }

    // rebuild full Q(:,l), q(l) on all 32 lanes of the batch
    float Qc[16];
    #pragma unroll
    for (int i=0;i<16;i++) Qc[i] = Qp[i] + __shfl_xor(Qp[i],16,64);
    float qv = qvp + __shfl_xor(qvp,16,64);

    if (h==0 && l>=12){
      const int cc=l-12;
      ((float4*)Quu)[cc] = make_float4(Qc[12],Qc[13],Qc[14],Qc[15]);
      float4* qx=(float4*)(Qxu + cc*12);
      qx[0]=make_float4(Qc[0],Qc[1],Qc[2],Qc[3]);
      qx[1]=make_float4(Qc[4],Qc[5],Qc[6],Qc[7]);
      qx[2]=make_float4(Qc[8],Qc[9],Qc[10],Qc[11]);
    }
    FENCE(); // B2: Quu/Qxu staged

    float qu0=__shfl(qv,gb32+12,64),qu1=__shfl(qv,gb32+13,64),
          qu2=__shfl(qv,gb32+14,64),qu3=__shfl(qv,gb32+15,64);
    float b0,b1,b2,b3;
    if (l<12){b0=-Qc[12];b1=-Qc[13];b2=-Qc[14];b3=-Qc[15];}
    else     {b0=-qu0;b1=-qu1;b2=-qu2;b3=-qu3;}

    const float4 quu0=((const float4*)Quu)[0], quu1=((const float4*)Quu)[1],
                 quu2=((const float4*)Quu)[2], quu3=((const float4*)Quu)[3];
    float a00=quu0.x,a10=quu0.y,a20=quu0.z,a30=quu0.w;
    float a01=quu1.x,a11=quu1.y,a21=quu1.z,a31=quu1.w;
    float a02=quu2.x,a12=quu2.y,a22=quu2.z,a32=quu2.w;
    float a03=quu3.x,a13=quu3.y,a23=quu3.z,a33=quu3.w;

    // 4x4 LU, no pivot (Quu SPD, diag >= 1)
    float i0=1.0f/a00;
    float m10=a10*i0,m20=a20*i0,m30=a30*i0;
    a11-=m10*a01;a12-=m10*a02;a13-=m10*a03;b1-=m10*b0;
    a21-=m20*a01;a22-=m20*a02;a23-=m20*a03;b2-=m20*b0;
    a31-=m30*a01;a32-=m30*a02;a33-=m30*a03;b3-=m30*b0;
    float i1=1.0f/a11;
    float m21=a21*i1,m31=a31*i1;
    a22-=m21*a12;a23-=m21*a13;b2-=m21*b1;
    a32-=m31*a12;a33-=m31*a13;b3-=m31*b1;
    float i2=1.0f/a22;
    float m32=a32*i2;
    a33-=m32*a23;b3-=m32*b2;
    float X3=b3/a33;
    float X2=(b2-a23*X3)*i2;
    float X1=(b1-a12*X2-a13*X3)*i1;
    float X0=(b0-a01*X1-a02*X2-a03*X3)*i0;

    if (h==0) storeK<KMODE>(wsv, (size_t)tt*BB+b, l, X0,X1,X2,X3);

    const float k0=__shfl(X0,gb32+12,64),k1=__shfl(X1,gb32+12,64),
                k2=__shfl(X2,gb32+12,64),k3=__shfl(X3,gb32+12,64);

    if (l<12){
      const int i0i=6*h;
      // Qxu rows for my i-range, per r: float2 reads (8B aligned)
      float Vn[6];
      #pragma unroll
      for (int k2=0;k2<6;k2++) Vn[k2] = h? Qc[6+k2] : Qc[k2];
      #pragma unroll
      for (int r=0;r<4;r++){
        const float Xr=(r==0)?X0:(r==1)?X1:(r==2)?X2:X3;
        const float2* qx2=(const float2*)(Qxu + r*12 + i0i);
        float2 x0=qx2[0],x1=qx2[1],x2=qx2[2];
        Vn[0]+=x0.x*Xr; Vn[1]+=x0.y*Xr; Vn[2]+=x1.x*Xr;
        Vn[3]+=x1.y*Xr; Vn[4]+=x2.x*Xr; Vn[5]+=x2.y*Xr;
      }
      // V update: no symmetrization round-trip (asymmetry ~1e-7, tolerance 6.04)
      #pragma unroll
      for (int k2=0;k2<6;k2++) V[(i0i+k2)*12+l]=Vn[k2];
      if (h==0){
        // vn via Q symmetry: Q[l][12+r] == Q[12+r][l] = Qc[12+r] (local)
        vv[l] = qv + Qc[12]*k0 + Qc[13]*k1 + Qc[14]*k2 + Qc[15]*k3;
      }
    }
    // V/vv WAR vs next iter: in-order wave LDS pipe + next B1 fence
  }

  // drain K/k stores before forward reads them
  asm volatile("s_waitcnt vmcnt(0)" ::: "memory");

  // ================= forward rollout (LDS-free, shfl-only) =================
  float xj = (h==0 && l<12)? xinit[(size_t)b*12+l] : 0.f;
  double costacc=0.0;

  float4 sF0=make_float4(0,0,0,0),sF1=sF0,sF2=sF0,sF3=sF0;
  float4 sK=make_float4(0,0,0,0); float sk_=0.f;
  {
    const float4* pc=(const float4*)(Cg + (size_t)b*256 + l*16);
    sCa=pc[2*h]; sCb=pc[2*h+1];
    sc_=cg[(size_t)b*16+l];
    if (h==0 && l<12){
      const float4* pf=(const float4*)(Fg + (size_t)b*192 + l*16);
      sF0=pf[0];sF1=pf[1];sF2=pf[2];sF3=pf[3];
      sf_=fg[(size_t)b*12+l];
      sK=loadKcol<KMODE>(wsv,(size_t)b,l);
    }
    if (h==0 && l>=12) sk_=loadkk<KMODE>(wsv,(size_t)b,l-12);
  }

  for (int t=0;t<TT;t++){
    float4 Ca=sCa,Cb=sCb; float rc=sc_;
    float4 F0=sF0,F1=sF1,F2=sF2,F3=sF3; float rf=sf_;
    float4 K4=sK; float kl=sk_;

    if (t+1<TT){
      const size_t of=((size_t)(t+1)*BB + b);
      const float4* pc=(const float4*)(Cg + of*256 + l*16);
      sCa=pc[2*h]; sCb=pc[2*h+1];
      sc_=cg[of*16+l];
      if (h==0 && l<12){
        sK=loadKcol<KMODE>(wsv,of,l);
        if (t+1<TT-1){
          const float4* pf=(const float4*)(Fg + of*192 + l*16);
          sF0=pf[0];sF1=pf[1];sF2=pf[2];sF3=pf[3];
          sf_=fg[of*12+l];
        }
      }
      if (h==0 && l>=12) sk_=loadkk<KMODE>(wsv,of,l-12);
    }

    // u = K x + k (reduction within h=0's 16-lane subgroup)
    float pr0=0.f,pr1=0.f,pr2=0.f,pr3=0.f;
    if (h==0 && l<12){ pr0=K4.x*xj; pr1=K4.y*xj; pr2=K4.z*xj; pr3=K4.w*xj; }
    #pragma unroll
    for (int m=1;m<16;m<<=1){
      pr0+=__shfl_xor(pr0,m,64); pr1+=__shfl_xor(pr1,m,64);
      pr2+=__shfl_xor(pr2,m,64); pr3+=__shfl_xor(pr3,m,64);
    }
    float tauj=0.f;
    if (h==0){
      if (l<12) tauj=xj;
      else {
        const float ur=(l==12)?pr0:(l==13)?pr1:(l==14)?pr2:pr3;
        tauj=ur+kl;
      }
    }
    // broadcast tau from h0 lanes to everyone (no LDS, no fence)
    float tau[16];
    #pragma unroll
    for (int j=0;j<16;j++) tau[j]=__shfl(tauj, gb32+j, 64);
    const float taul=__shfl(tauj, gb32+l, 64);

    // my half's tau rows [8h, 8h+8)
    float t8[8];
    #pragma unroll
    for (int j=0;j<8;j++) t8[j] = h? tau[8+j] : tau[j];

    // cost partial: 0.5 * tau_l * sum_{j in half} C[j][l] tau_j (+ c_l tau_l on h0)
    float dot_p = Ca.x*t8[0] + Ca.y*t8[1] + Ca.z*t8[2] + Ca.w*t8[3]
                + Cb.x*t8[4] + Cb.y*t8[5] + Cb.z*t8[6] + Cb.w*t8[7];
    costacc += (double)( taul*0.5f*dot_p + (h==0 ? taul*rc : 0.f) );

    if (h==0){
      if (l<12) out[(size_t)t*BB*12 + (size_t)b*12 + l] = xj;
      else      out[(size_t)TT*BB*12 + (size_t)t*BB*4 + (size_t)b*4 + (l-12)] = tauj;
    }

    if (t<TT-1 && h==0 && l<12){
      xj = rf
         + F0.x*tau[0]+F0.y*tau[1]+F0.z*tau[2]+F0.w*tau[3]
         + F1.x*tau[4]+F1.y*tau[5]+F1.z*tau[6]+F1.w*tau[7]
         + F2.x*tau[8]+F2.y*tau[9]+F2.z*tau[10]+F2.w*tau[11]
         + F3.x*tau[12]+F3.y*tau[13]+F3.z*tau[14]+F3.w*tau[15];
    }
  }

  costacc+=__shfl_xor(costacc,1,64); costacc+=__shfl_xor(costacc,2,64);
  costacc+=__shfl_xor(costacc,4,64); costacc+=__shfl_xor(costacc,8,64);
  costacc+=__shfl_xor(costacc,16,64);
  if (h==0 && l==0) out[(size_t)TT*BB*16 + b]=(float)costacc;
}

extern "C" void kernel_launch(void* const* d_in, const int* in_sizes, int n_in,
                              void* d_out, int out_size, void* d_ws, size_t ws_size,
                              hipStream_t stream){
  (void)in_sizes; (void)n_in; (void)out_size;
  const float* xinit=(const float*)d_in[0];
  const float* C    =(const float*)d_in[1];
  const float* c    =(const float*)d_in[2];
  const float* F    =(const float*)d_in[3];
  const float* f    =(const float*)d_in[4];
  const size_t need_f32 = (size_t)TT*BB*52*sizeof(float);   // 85.2 MB
  if (ws_size >= need_f32){
    lqr_fused<0><<<dim3(BB/8), dim3(256), 0, stream>>>(xinit,C,c,F,f,(float*)d_out,d_ws);
  } else {
    lqr_fused<1><<<dim3(BB/8), dim3(256), 0, stream>>>(xinit,C,c,F,f,(float*)d_out,d_ws);
  }
}

// Round 6
// 441.959 us; speedup vs baseline: 1.2017x; 1.2017x over previous
//
#include <hip/hip_runtime.h>
#include <hip/hip_fp16.h>

#define TT 100
#define BB 4096
#define GS 520   // floats per batch blob; 520 % 32 == 8 -> bank stagger

// per-batch float layout:
//   V   [0,144)     12x12 value matrix (row-addressed, NOT symmetrized)
//   Fl  [144,384)   12 rows x stride 20
//   Qxu [384,432)   Qxu[r*12+i] = Q[i][12+r]
//   Quu [432,448)   col-major 4x4
//   vv  [448,460)   v
//   tb  [460,492)   ft (backward) / 2x16 tau ping-pong (forward)

// wave-internal LDS fence: batch lives in one wave; no s_barrier needed.
#define FENCE() asm volatile("s_waitcnt lgkmcnt(0)" ::: "memory")

template<int KMODE>
__device__ __forceinline__ void storeK(void* wsv, size_t of, int l, float X0,float X1,float X2,float X3){
  if (KMODE==0){
    float* wsb=(float*)wsv + of*52;
    if (l<12)       ((float4*)wsb)[l]  = make_float4(X0,X1,X2,X3);
    else if (l==12) ((float4*)wsb)[12] = make_float4(X0,X1,X2,X3);
  } else {
    __half* wsb=(__half*)wsv + of*52;
    if (l<12){
      wsb[l*4+0]=__float2half(X0); wsb[l*4+1]=__float2half(X1);
      wsb[l*4+2]=__float2half(X2); wsb[l*4+3]=__float2half(X3);
    } else if (l==12){
      wsb[48]=__float2half(X0); wsb[49]=__float2half(X1);
      wsb[50]=__float2half(X2); wsb[51]=__float2half(X3);
    }
  }
}
template<int KMODE>
__device__ __forceinline__ float4 loadKcol(const void* wsv, size_t of, int l){
  if (KMODE==0) return ((const float4*)((const float*)wsv + of*52))[l];
  const __half* p=(const __half*)wsv + of*52 + l*4;
  return make_float4(__half2float(p[0]),__half2float(p[1]),__half2float(p[2]),__half2float(p[3]));
}
template<int KMODE>
__device__ __forceinline__ float loadkk(const void* wsv, size_t of, int r){
  if (KMODE==0) return ((const float*)wsv)[of*52+48+r];
  return __half2float(((const __half*)wsv)[of*52+48+r]);
}

template<int KMODE>
__global__ __launch_bounds__(256)
void lqr_fused(const float* __restrict__ xinit,
               const float* __restrict__ Cg,
               const float* __restrict__ cg,
               const float* __restrict__ Fg,
               const float* __restrict__ fg,
               float* __restrict__ out,
               void* __restrict__ wsv)
{
  __shared__ float smem[GS*8];
  const int tid  = threadIdx.x;
  const int gi   = tid >> 5;        // batch group in block (0..7)
  const int lane = tid & 63;
  const int l    = tid & 15;        // column
  const int h    = (tid >> 4) & 1;  // half (s/i ranges [6h,6h+6), C rows [8h,8h+8))
  const int b    = blockIdx.x*8 + gi;
  const int gb32 = lane & ~31;      // batch base lane within wave

  float* __restrict__ V   = smem + gi*GS;
  float* __restrict__ Fl  = V + 144;
  float* __restrict__ Qxu = V + 384;
  float* __restrict__ Quu = V + 432;
  float* __restrict__ vv  = V + 448;
  float* __restrict__ tb  = V + 460;

  // ================= backward Riccati =================
  float4 sCa,sCb; float sc_;
  float4 sFa=make_float4(0,0,0,0),sFb=sFa; float sf_=0.f;
  {
    const size_t of = ((size_t)(TT-1)*BB + b);
    const float4* pc = (const float4*)(Cg + of*256 + l*16);
    sCa=pc[2*h]; sCb=pc[2*h+1];      // C col l, rows [8h,8h+8)
    sc_ = cg[of*16 + l];
  }

  for (int tt=TT-1; tt>=0; --tt){
    const bool hasF = (tt < TT-1);
    float4 Ca=sCa,Cb=sCb; float rc=sc_;
    float4 Fa=sFa,Fb=sFb; float rf=sf_;

    if (hasF && l<12){
      float4* q=(float4*)(Fl + l*20);
      q[2*h]=Fa; q[2*h+1]=Fb;        // h0: cols 0-7, h1: cols 8-15 of row l
      if (h==0) tb[l]=rf;
    }
    FENCE(); // B1: Fl/tb staged; prev-iter V/vv writes visible

    if (tt>0){
      const size_t of = ((size_t)(tt-1)*BB + b);
      const float4* pc=(const float4*)(Cg + of*256 + l*16);
      sCa=pc[2*h]; sCb=pc[2*h+1];
      sc_=cg[of*16+l];
      if (l<12){
        const float4* pf=(const float4*)(Fg + of*192 + l*16);
        sFa=pf[2*h]; sFb=pf[2*h+1];
        if (h==0) sf_=fg[of*12+l];
      }
    }

    // partial Q column (C added on owning half's rows)
    const float R0=Ca.x,R1=Ca.y,R2=Ca.z,R3=Ca.w,R4=Cb.x,R5=Cb.y,R6=Cb.z,R7=Cb.w;
    float Qp[16];
    Qp[0]=h?0.f:R0; Qp[1]=h?0.f:R1; Qp[2]=h?0.f:R2; Qp[3]=h?0.f:R3;
    Qp[4]=h?0.f:R4; Qp[5]=h?0.f:R5; Qp[6]=h?0.f:R6; Qp[7]=h?0.f:R7;
    Qp[8]=h?R0:0.f; Qp[9]=h?R1:0.f; Qp[10]=h?R2:0.f; Qp[11]=h?R3:0.f;
    Qp[12]=h?R4:0.f; Qp[13]=h?R5:0.f; Qp[14]=h?R6:0.f; Qp[15]=h?R7:0.f;
    float qvp = h? 0.f : rc;

    if (hasF){
      float FtL[6], FtH[6];
      #pragma unroll
      for (int k2=0;k2<6;k2++){ FtL[k2]=Fl[k2*20+l]; FtH[k2]=Fl[(6+k2)*20+l]; }
      const int s0=6*h;
      float Wl[6];
      #pragma unroll
      for (int k2=0;k2<6;k2++){
        const float4* vr=(const float4*)(V+(s0+k2)*12);
        float4 v0=vr[0],v1=vr[1],v2=vr[2];
        Wl[k2]= v0.x*FtL[0]+v0.y*FtL[1]+v0.z*FtL[2]+v0.w*FtL[3]
              + v1.x*FtL[4]+v1.y*FtL[5]+v1.z*FtH[0]+v1.w*FtH[1]
              + v2.x*FtH[2]+v2.y*FtH[3]+v2.z*FtH[4]+v2.w*FtH[5];
      }
      #pragma unroll
      for (int k2=0;k2<6;k2++){
        const float4* fr=(const float4*)(Fl + (s0+k2)*20);
        float4 f0=fr[0],f1=fr[1],f2=fr[2],f3=fr[3];
        float w=Wl[k2];
        Qp[0]+=f0.x*w;  Qp[1]+=f0.y*w;  Qp[2]+=f0.z*w;  Qp[3]+=f0.w*w;
        Qp[4]+=f1.x*w;  Qp[5]+=f1.y*w;  Qp[6]+=f1.z*w;  Qp[7]+=f1.w*w;
        Qp[8]+=f2.x*w;  Qp[9]+=f2.y*w;  Qp[10]+=f2.z*w; Qp[11]+=f2.w*w;
        Qp[12]+=f3.x*w; Qp[13]+=f3.y*w; Qp[14]+=f3.z*w; Qp[15]+=f3.w*w;
      }
      #pragma unroll
      for (int k2=0;k2<6;k2++){
        qvp += Wl[k2]*tb[s0+k2];
        const float ftk = h? FtH[k2] : FtL[k2];
        qvp += ftk * vv[s0+k2];
      }
    }

    // rebuild full Q(:,l), q(l) on all 32 lanes of the batch
    float Qc[16];
    #pragma unroll
    for (int i=0;i<16;i++) Qc[i] = Qp[i] + __shfl_xor(Qp[i],16,64);
    float qv = qvp + __shfl_xor(qvp,16,64);

    if (h==0 && l>=12){
      const int cc=l-12;
      ((float4*)Quu)[cc] = make_float4(Qc[12],Qc[13],Qc[14],Qc[15]);
      float4* qx=(float4*)(Qxu + cc*12);
      qx[0]=make_float4(Qc[0],Qc[1],Qc[2],Qc[3]);
      qx[1]=make_float4(Qc[4],Qc[5],Qc[6],Qc[7]);
      qx[2]=make_float4(Qc[8],Qc[9],Qc[10],Qc[11]);
    }
    FENCE(); // B2: Quu/Qxu staged

    float qu0=__shfl(qv,gb32+12,64),qu1=__shfl(qv,gb32+13,64),
          qu2=__shfl(qv,gb32+14,64),qu3=__shfl(qv,gb32+15,64);
    float b0,b1,b2,b3;
    if (l<12){b0=-Qc[12];b1=-Qc[13];b2=-Qc[14];b3=-Qc[15];}
    else     {b0=-qu0;b1=-qu1;b2=-qu2;b3=-qu3;}

    const float4 quu0=((const float4*)Quu)[0], quu1=((const float4*)Quu)[1],
                 quu2=((const float4*)Quu)[2], quu3=((const float4*)Quu)[3];
    float a00=quu0.x,a10=quu0.y,a20=quu0.z,a30=quu0.w;
    float a01=quu1.x,a11=quu1.y,a21=quu1.z,a31=quu1.w;
    float a02=quu2.x,a12=quu2.y,a22=quu2.z,a32=quu2.w;
    float a03=quu3.x,a13=quu3.y,a23=quu3.z,a33=quu3.w;

    // 4x4 LU, no pivot (Quu SPD, diag >= 1)
    float i0=1.0f/a00;
    float m10=a10*i0,m20=a20*i0,m30=a30*i0;
    a11-=m10*a01;a12-=m10*a02;a13-=m10*a03;b1-=m10*b0;
    a21-=m20*a01;a22-=m20*a02;a23-=m20*a03;b2-=m20*b0;
    a31-=m30*a01;a32-=m30*a02;a33-=m30*a03;b3-=m30*b0;
    float i1=1.0f/a11;
    float m21=a21*i1,m31=a31*i1;
    a22-=m21*a12;a23-=m21*a13;b2-=m21*b1;
    a32-=m31*a12;a33-=m31*a13;b3-=m31*b1;
    float i2=1.0f/a22;
    float m32=a32*i2;
    a33-=m32*a23;b3-=m32*b2;
    float X3=b3/a33;
    float X2=(b2-a23*X3)*i2;
    float X1=(b1-a12*X2-a13*X3)*i1;
    float X0=(b0-a01*X1-a02*X2-a03*X3)*i0;

    if (h==0) storeK<KMODE>(wsv, (size_t)tt*BB+b, l, X0,X1,X2,X3);

    const float k0=__shfl(X0,gb32+12,64),k1=__shfl(X1,gb32+12,64),
                k2=__shfl(X2,gb32+12,64),k3=__shfl(X3,gb32+12,64);

    if (l<12){
      const int i0i=6*h;
      float Vn[6];
      #pragma unroll
      for (int k2=0;k2<6;k2++) Vn[k2] = h? Qc[6+k2] : Qc[k2];
      #pragma unroll
      for (int r=0;r<4;r++){
        const float Xr=(r==0)?X0:(r==1)?X1:(r==2)?X2:X3;
        const float2* qx2=(const float2*)(Qxu + r*12 + i0i);
        float2 x0=qx2[0],x1=qx2[1],x2=qx2[2];
        Vn[0]+=x0.x*Xr; Vn[1]+=x0.y*Xr; Vn[2]+=x1.x*Xr;
        Vn[3]+=x1.y*Xr; Vn[4]+=x2.x*Xr; Vn[5]+=x2.y*Xr;
      }
      // no symmetrization round-trip (asymmetry ~1e-7, tolerance 6.04)
      #pragma unroll
      for (int k2=0;k2<6;k2++) V[(i0i+k2)*12+l]=Vn[k2];
      if (h==0){
        // vn via Q symmetry: Q[l][12+r] == Q[12+r][l] = Qc[12+r] (local)
        vv[l] = qv + Qc[12]*k0 + Qc[13]*k1 + Qc[14]*k2 + Qc[15]*k3;
      }
    }
    // V/vv WAR vs next iter: in-order wave LDS pipe + next B1 fence
  }

  // drain K/k stores before forward reads them
  asm volatile("s_waitcnt vmcnt(0)" ::: "memory");

  // ================= forward rollout (R4 structure: LDS tau ping-pong) ====
  float xj = (h==0 && l<12)? xinit[(size_t)b*12+l] : 0.f;
  double costacc=0.0;

  float4 sF0=make_float4(0,0,0,0),sF1=sF0,sF2=sF0,sF3=sF0;
  float4 sK=make_float4(0,0,0,0); float sk_=0.f;
  {
    const float4* pc=(const float4*)(Cg + (size_t)b*256 + l*16);
    sCa=pc[2*h]; sCb=pc[2*h+1];
    sc_=cg[(size_t)b*16+l];
    if (h==0 && l<12){
      const float4* pf=(const float4*)(Fg + (size_t)b*192 + l*16);
      sF0=pf[0];sF1=pf[1];sF2=pf[2];sF3=pf[3];
      sf_=fg[(size_t)b*12+l];
      sK=loadKcol<KMODE>(wsv,(size_t)b,l);
    }
    if (h==0 && l>=12) sk_=loadkk<KMODE>(wsv,(size_t)b,l-12);
  }

  for (int t=0;t<TT;t++){
    float4 Ca=sCa,Cb=sCb; float rc=sc_;
    float4 F0=sF0,F1=sF1,F2=sF2,F3=sF3; float rf=sf_;
    float4 K4=sK; float kl=sk_;

    if (t+1<TT){
      const size_t of=((size_t)(t+1)*BB + b);
      const float4* pc=(const float4*)(Cg + of*256 + l*16);
      sCa=pc[2*h]; sCb=pc[2*h+1];
      sc_=cg[of*16+l];
      if (h==0 && l<12){
        sK=loadKcol<KMODE>(wsv,of,l);
        if (t+1<TT-1){
          const float4* pf=(const float4*)(Fg + of*192 + l*16);
          sF0=pf[0];sF1=pf[1];sF2=pf[2];sF3=pf[3];
          sf_=fg[of*12+l];
        }
      }
      if (h==0 && l>=12) sk_=loadkk<KMODE>(wsv,of,l-12);
    }

    // u = K x + k (reduction within h=0's 16-lane subgroup)
    float pr0=0.f,pr1=0.f,pr2=0.f,pr3=0.f;
    if (h==0 && l<12){ pr0=K4.x*xj; pr1=K4.y*xj; pr2=K4.z*xj; pr3=K4.w*xj; }
    #pragma unroll
    for (int m=1;m<16;m<<=1){
      pr0+=__shfl_xor(pr0,m,64); pr1+=__shfl_xor(pr1,m,64);
      pr2+=__shfl_xor(pr2,m,64); pr3+=__shfl_xor(pr3,m,64);
    }
    float* tbuf = tb + (t&1)*16;
    float tauj=0.f;
    if (h==0){
      if (l<12) tauj=xj;
      else {
        const float ur=(l==12)?pr0:(l==13)?pr1:(l==14)?pr2:pr3;
        tauj=ur+kl;
      }
      tbuf[l]=tauj;
    }
    FENCE(); // tau staged

    const float4* tp=(const float4*)tbuf;
    const float4 ta=tp[2*h], tb4=tp[2*h+1];   // tau rows [8h,8h+8)
    const float taul = tbuf[l];

    // cost partial: 0.5 * tau_l * sum_{j in half} C[j][l] tau_j (+ c_l tau_l on h0)
    float dot_p = Ca.x*ta.x + Ca.y*ta.y + Ca.z*ta.z + Ca.w*ta.w
                + Cb.x*tb4.x + Cb.y*tb4.y + Cb.z*tb4.z + Cb.w*tb4.w;
    costacc += (double)( taul*0.5f*dot_p + (h==0 ? taul*rc : 0.f) );

    if (h==0){
      if (l<12) out[(size_t)t*BB*12 + (size_t)b*12 + l] = xj;
      else      out[(size_t)TT*BB*12 + (size_t)t*BB*4 + (size_t)b*4 + (l-12)] = tauj;
    }

    if (t<TT-1 && h==0 && l<12){
      const float4 t0=tp[0],t1=tp[1],t2=tp[2],t3=tp[3];
      xj = rf
         + F0.x*t0.x+F0.y*t0.y+F0.z*t0.z+F0.w*t0.w
         + F1.x*t1.x+F1.y*t1.y+F1.z*t1.z+F1.w*t1.w
         + F2.x*t2.x+F2.y*t2.y+F2.z*t2.z+F2.w*t2.w
         + F3.x*t3.x+F3.y*t3.y+F3.z*t3.z+F3.w*t3.w;
    }
    // tau WAR across iters: ping-pong buffer
  }

  costacc+=__shfl_xor(costacc,1,64); costacc+=__shfl_xor(costacc,2,64);
  costacc+=__shfl_xor(costacc,4,64); costacc+=__shfl_xor(costacc,8,64);
  costacc+=__shfl_xor(costacc,16,64);
  if (h==0 && l==0) out[(size_t)TT*BB*16 + b]=(float)costacc;
}

extern "C" void kernel_launch(void* const* d_in, const int* in_sizes, int n_in,
                              void* d_out, int out_size, void* d_ws, size_t ws_size,
                              hipStream_t stream){
  (void)in_sizes; (void)n_in; (void)out_size;
  const float* xinit=(const float*)d_in[0];
  const float* C    =(const float*)d_in[1];
  const float* c    =(const float*)d_in[2];
  const float* F    =(const float*)d_in[3];
  const float* f    =(const float*)d_in[4];
  const size_t need_f32 = (size_t)TT*BB*52*sizeof(float);   // 85.2 MB
  if (ws_size >= need_f32){
    lqr_fused<0><<<dim3(BB/8), dim3(256), 0, stream>>>(xinit,C,c,F,f,(float*)d_out,d_ws);
  } else {
    lqr_fused<1><<<dim3(BB/8), dim3(256), 0, stream>>>(xinit,C,c,F,f,(float*)d_out,d_ws);
  }
}

// Round 7
// 441.667 us; speedup vs baseline: 1.2025x; 1.0007x over previous
//
#include <hip/hip_runtime.h>
#include <hip/hip_fp16.h>

#define TT 100
#define BB 4096
#define GS 520   // floats per batch blob; 520 % 32 == 8 -> bank stagger

// per-batch float layout:
//   V   [0,144)     12x12 value matrix (row-addressed, NOT symmetrized)
//   Fl  [144,384)   12 rows x stride 20
//   Qxu [384,432)   Qxu[r*12+i] = Q[i][12+r]
//   Quu [432,448)   col-major 4x4
//   vv  [448,460)   v
//   tb  [460,492)   ft (backward) / 2x16 tau ping-pong (forward)
//
// Lane layout (R7): batch = 32 lanes at {base16 + 0..15} (h=0) and
// {base16+32 .. +47} (h=1), base16 = lane&16. The h-split is lane^32 so the
// half-sum rebuild uses v_permlane32_swap (VALU pipe) instead of ds_swizzle
// (DS pipe) — DS pipe is the measured bottleneck (R6: ~90% util, VALU 40%).

// wave-internal LDS fence: batch lives in one wave; no s_barrier needed.
#define FENCE() asm volatile("s_waitcnt lgkmcnt(0)" ::: "memory")

// x + x[lane^32], via VALU (robust: a'+b' is the pair-sum under any half-swap)
__device__ __forceinline__ float pairsum32(float x){
  float a=x, b=x;
  asm("v_permlane32_swap_b32 %0, %1" : "+v"(a), "+v"(b));
  return a+b;
}

template<int KMODE>
__device__ __forceinline__ void storeK(void* wsv, size_t of, int l, float X0,float X1,float X2,float X3){
  if (KMODE==0){
    float* wsb=(float*)wsv + of*52;
    if (l<12)       ((float4*)wsb)[l]  = make_float4(X0,X1,X2,X3);
    else if (l==12) ((float4*)wsb)[12] = make_float4(X0,X1,X2,X3);
  } else {
    __half* wsb=(__half*)wsv + of*52;
    if (l<12){
      wsb[l*4+0]=__float2half(X0); wsb[l*4+1]=__float2half(X1);
      wsb[l*4+2]=__float2half(X2); wsb[l*4+3]=__float2half(X3);
    } else if (l==12){
      wsb[48]=__float2half(X0); wsb[49]=__float2half(X1);
      wsb[50]=__float2half(X2); wsb[51]=__float2half(X3);
    }
  }
}
template<int KMODE>
__device__ __forceinline__ float4 loadKcol(const void* wsv, size_t of, int l){
  if (KMODE==0) return ((const float4*)((const float*)wsv + of*52))[l];
  const __half* p=(const __half*)wsv + of*52 + l*4;
  return make_float4(__half2float(p[0]),__half2float(p[1]),__half2float(p[2]),__half2float(p[3]));
}
template<int KMODE>
__device__ __forceinline__ float loadkk(const void* wsv, size_t of, int r){
  if (KMODE==0) return ((const float*)wsv)[of*52+48+r];
  return __half2float(((const __half*)wsv)[of*52+48+r]);
}

template<int KMODE>
__global__ __launch_bounds__(256)
void lqr_fused(const float* __restrict__ xinit,
               const float* __restrict__ Cg,
               const float* __restrict__ cg,
               const float* __restrict__ Fg,
               const float* __restrict__ fg,
               float* __restrict__ out,
               void* __restrict__ wsv)
{
  __shared__ float smem[GS*8];
  const int tid    = threadIdx.x;
  const int lane   = tid & 63;
  const int l      = lane & 15;        // column
  const int h      = lane >> 5;        // half (s/i ranges [6h,6h+6), C rows [8h,8h+8))
  const int w      = (lane >> 4) & 1;  // batch within wave
  const int gi     = (tid >> 6)*2 + w; // batch within block (0..7)
  const int b      = blockIdx.x*8 + gi;
  const int base16 = lane & 16;        // lane index of my batch's h0 sub-group base

  float* __restrict__ V   = smem + gi*GS;
  float* __restrict__ Fl  = V + 144;
  float* __restrict__ Qxu = V + 384;
  float* __restrict__ Quu = V + 432;
  float* __restrict__ vv  = V + 448;
  float* __restrict__ tb  = V + 460;

  // ================= backward Riccati =================
  float4 sCa,sCb; float sc_;
  float4 sFa=make_float4(0,0,0,0),sFb=sFa; float sf_=0.f;
  {
    const size_t of = ((size_t)(TT-1)*BB + b);
    const float4* pc = (const float4*)(Cg + of*256 + l*16);
    sCa=pc[2*h]; sCb=pc[2*h+1];      // C col l, rows [8h,8h+8)
    sc_ = cg[of*16 + l];
  }

  for (int tt=TT-1; tt>=0; --tt){
    const bool hasF = (tt < TT-1);
    float4 Ca=sCa,Cb=sCb; float rc=sc_;
    float4 Fa=sFa,Fb=sFb; float rf=sf_;

    if (hasF && l<12){
      float4* q=(float4*)(Fl + l*20);
      q[2*h]=Fa; q[2*h+1]=Fb;        // h0: cols 0-7, h1: cols 8-15 of row l
      if (h==0) tb[l]=rf;
    }
    FENCE(); // B1: Fl/tb staged; prev-iter V/vv writes visible

    if (tt>0){
      const size_t of = ((size_t)(tt-1)*BB + b);
      const float4* pc=(const float4*)(Cg + of*256 + l*16);
      sCa=pc[2*h]; sCb=pc[2*h+1];
      sc_=cg[of*16+l];
      if (l<12){
        const float4* pf=(const float4*)(Fg + of*192 + l*16);
        sFa=pf[2*h]; sFb=pf[2*h+1];
        if (h==0) sf_=fg[of*12+l];
      }
    }

    // partial Q column (C added on owning half's rows)
    const float R0=Ca.x,R1=Ca.y,R2=Ca.z,R3=Ca.w,R4=Cb.x,R5=Cb.y,R6=Cb.z,R7=Cb.w;
    float Qp[16];
    Qp[0]=h?0.f:R0; Qp[1]=h?0.f:R1; Qp[2]=h?0.f:R2; Qp[3]=h?0.f:R3;
    Qp[4]=h?0.f:R4; Qp[5]=h?0.f:R5; Qp[6]=h?0.f:R6; Qp[7]=h?0.f:R7;
    Qp[8]=h?R0:0.f; Qp[9]=h?R1:0.f; Qp[10]=h?R2:0.f; Qp[11]=h?R3:0.f;
    Qp[12]=h?R4:0.f; Qp[13]=h?R5:0.f; Qp[14]=h?R6:0.f; Qp[15]=h?R7:0.f;
    float qvp = h? 0.f : rc;

    if (hasF){
      float FtL[6], FtH[6];
      #pragma unroll
      for (int k2=0;k2<6;k2++){ FtL[k2]=Fl[k2*20+l]; FtH[k2]=Fl[(6+k2)*20+l]; }
      const int s0=6*h;
      float Wl[6];
      #pragma unroll
      for (int k2=0;k2<6;k2++){
        const float4* vr=(const float4*)(V+(s0+k2)*12);
        float4 v0=vr[0],v1=vr[1],v2=vr[2];
        Wl[k2]= v0.x*FtL[0]+v0.y*FtL[1]+v0.z*FtL[2]+v0.w*FtL[3]
              + v1.x*FtL[4]+v1.y*FtL[5]+v1.z*FtH[0]+v1.w*FtH[1]
              + v2.x*FtH[2]+v2.y*FtH[3]+v2.z*FtH[4]+v2.w*FtH[5];
      }
      #pragma unroll
      for (int k2=0;k2<6;k2++){
        const float4* fr=(const float4*)(Fl + (s0+k2)*20);
        float4 f0=fr[0],f1=fr[1],f2=fr[2],f3=fr[3];
        float w2=Wl[k2];
        Qp[0]+=f0.x*w2;  Qp[1]+=f0.y*w2;  Qp[2]+=f0.z*w2;  Qp[3]+=f0.w*w2;
        Qp[4]+=f1.x*w2;  Qp[5]+=f1.y*w2;  Qp[6]+=f1.z*w2;  Qp[7]+=f1.w*w2;
        Qp[8]+=f2.x*w2;  Qp[9]+=f2.y*w2;  Qp[10]+=f2.z*w2; Qp[11]+=f2.w*w2;
        Qp[12]+=f3.x*w2; Qp[13]+=f3.y*w2; Qp[14]+=f3.z*w2; Qp[15]+=f3.w*w2;
      }
      #pragma unroll
      for (int k2=0;k2<6;k2++){
        qvp += Wl[k2]*tb[s0+k2];
        const float ftk = h? FtH[k2] : FtL[k2];
        qvp += ftk * vv[s0+k2];
      }
    }

    // rebuild full Q(:,l), q(l) on all 32 lanes: VALU pair-sum (lane^32)
    float Qc[16];
    #pragma unroll
    for (int i=0;i<16;i++) Qc[i] = pairsum32(Qp[i]);
    float qv = pairsum32(qvp);

    if (h==0 && l>=12){
      const int cc=l-12;
      ((float4*)Quu)[cc] = make_float4(Qc[12],Qc[13],Qc[14],Qc[15]);
      float4* qx=(float4*)(Qxu + cc*12);
      qx[0]=make_float4(Qc[0],Qc[1],Qc[2],Qc[3]);
      qx[1]=make_float4(Qc[4],Qc[5],Qc[6],Qc[7]);
      qx[2]=make_float4(Qc[8],Qc[9],Qc[10],Qc[11]);
    }
    FENCE(); // B2: Quu/Qxu staged

    float qu0=__shfl(qv,base16+12,64),qu1=__shfl(qv,base16+13,64),
          qu2=__shfl(qv,base16+14,64),qu3=__shfl(qv,base16+15,64);
    float b0,b1,b2,b3;
    if (l<12){b0=-Qc[12];b1=-Qc[13];b2=-Qc[14];b3=-Qc[15];}
    else     {b0=-qu0;b1=-qu1;b2=-qu2;b3=-qu3;}

    const float4 quu0=((const float4*)Quu)[0], quu1=((const float4*)Quu)[1],
                 quu2=((const float4*)Quu)[2], quu3=((const float4*)Quu)[3];
    float a00=quu0.x,a10=quu0.y,a20=quu0.z,a30=quu0.w;
    float a01=quu1.x,a11=quu1.y,a21=quu1.z,a31=quu1.w;
    float a02=quu2.x,a12=quu2.y,a22=quu2.z,a32=quu2.w;
    float a03=quu3.x,a13=quu3.y,a23=quu3.z,a33=quu3.w;

    // 4x4 LU, no pivot (Quu SPD, diag >= 1)
    float i0=1.0f/a00;
    float m10=a10*i0,m20=a20*i0,m30=a30*i0;
    a11-=m10*a01;a12-=m10*a02;a13-=m10*a03;b1-=m10*b0;
    a21-=m20*a01;a22-=m20*a02;a23-=m20*a03;b2-=m20*b0;
    a31-=m30*a01;a32-=m30*a02;a33-=m30*a03;b3-=m30*b0;
    float i1=1.0f/a11;
    float m21=a21*i1,m31=a31*i1;
    a22-=m21*a12;a23-=m21*a13;b2-=m21*b1;
    a32-=m31*a12;a33-=m31*a13;b3-=m31*b1;
    float i2=1.0f/a22;
    float m32=a32*i2;
    a33-=m32*a23;b3-=m32*b2;
    float X3=b3/a33;
    float X2=(b2-a23*X3)*i2;
    float X1=(b1-a12*X2-a13*X3)*i1;
    float X0=(b0-a01*X1-a02*X2-a03*X3)*i0;

    if (h==0) storeK<KMODE>(wsv, (size_t)tt*BB+b, l, X0,X1,X2,X3);

    const float k0=__shfl(X0,base16+12,64),k1=__shfl(X1,base16+12,64),
                k2=__shfl(X2,base16+12,64),k3=__shfl(X3,base16+12,64);

    if (l<12){
      const int i0i=6*h;
      float Vn[6];
      #pragma unroll
      for (int k2=0;k2<6;k2++) Vn[k2] = h? Qc[6+k2] : Qc[k2];
      #pragma unroll
      for (int r=0;r<4;r++){
        const float Xr=(r==0)?X0:(r==1)?X1:(r==2)?X2:X3;
        const float2* qx2=(const float2*)(Qxu + r*12 + i0i);
        float2 x0=qx2[0],x1=qx2[1],x2=qx2[2];
        Vn[0]+=x0.x*Xr; Vn[1]+=x0.y*Xr; Vn[2]+=x1.x*Xr;
        Vn[3]+=x1.y*Xr; Vn[4]+=x2.x*Xr; Vn[5]+=x2.y*Xr;
      }
      // no symmetrization round-trip (asymmetry ~1e-7, tolerance 6.04)
      #pragma unroll
      for (int k2=0;k2<6;k2++) V[(i0i+k2)*12+l]=Vn[k2];
      if (h==0){
        // vn via Q symmetry: Q[l][12+r] == Q[12+r][l] = Qc[12+r] (local)
        vv[l] = qv + Qc[12]*k0 + Qc[13]*k1 + Qc[14]*k2 + Qc[15]*k3;
      }
    }
    // V/vv WAR vs next iter: in-order wave LDS pipe + next B1 fence
  }

  // drain K/k stores before forward reads them
  asm volatile("s_waitcnt vmcnt(0)" ::: "memory");

  // ================= forward rollout (LDS tau ping-pong) =================
  float xj = (h==0 && l<12)? xinit[(size_t)b*12+l] : 0.f;
  double costacc=0.0;

  float4 sF0=make_float4(0,0,0,0),sF1=sF0,sF2=sF0,sF3=sF0;
  float4 sK=make_float4(0,0,0,0); float sk_=0.f;
  {
    const float4* pc=(const float4*)(Cg + (size_t)b*256 + l*16);
    sCa=pc[2*h]; sCb=pc[2*h+1];
    sc_=cg[(size_t)b*16+l];
    if (h==0 && l<12){
      const float4* pf=(const float4*)(Fg + (size_t)b*192 + l*16);
      sF0=pf[0];sF1=pf[1];sF2=pf[2];sF3=pf[3];
      sf_=fg[(size_t)b*12+l];
      sK=loadKcol<KMODE>(wsv,(size_t)b,l);
    }
    if (h==0 && l>=12) sk_=loadkk<KMODE>(wsv,(size_t)b,l-12);
  }

  for (int t=0;t<TT;t++){
    float4 Ca=sCa,Cb=sCb; float rc=sc_;
    float4 F0=sF0,F1=sF1,F2=sF2,F3=sF3; float rf=sf_;
    float4 K4=sK; float kl=sk_;

    if (t+1<TT){
      const size_t of=((size_t)(t+1)*BB + b);
      const float4* pc=(const float4*)(Cg + of*256 + l*16);
      sCa=pc[2*h]; sCb=pc[2*h+1];
      sc_=cg[of*16+l];
      if (h==0 && l<12){
        sK=loadKcol<KMODE>(wsv,of,l);
        if (t+1<TT-1){
          const float4* pf=(const float4*)(Fg + of*192 + l*16);
          sF0=pf[0];sF1=pf[1];sF2=pf[2];sF3=pf[3];
          sf_=fg[of*12+l];
        }
      }
      if (h==0 && l>=12) sk_=loadkk<KMODE>(wsv,of,l-12);
    }

    // u = K x + k (reduction within h=0's 16-lane subgroup)
    float pr0=0.f,pr1=0.f,pr2=0.f,pr3=0.f;
    if (h==0 && l<12){ pr0=K4.x*xj; pr1=K4.y*xj; pr2=K4.z*xj; pr3=K4.w*xj; }
    #pragma unroll
    for (int m=1;m<16;m<<=1){
      pr0+=__shfl_xor(pr0,m,64); pr1+=__shfl_xor(pr1,m,64);
      pr2+=__shfl_xor(pr2,m,64); pr3+=__shfl_xor(pr3,m,64);
    }
    float* tbuf = tb + (t&1)*16;
    float tauj=0.f;
    if (h==0){
      if (l<12) tauj=xj;
      else {
        const float ur=(l==12)?pr0:(l==13)?pr1:(l==14)?pr2:pr3;
        tauj=ur+kl;
      }
      tbuf[l]=tauj;
    }
    FENCE(); // tau staged

    const float4* tp=(const float4*)tbuf;
    const float4 ta=tp[2*h], tb4=tp[2*h+1];   // tau rows [8h,8h+8)
    const float taul = tbuf[l];

    // cost partial: 0.5 * tau_l * sum_{j in half} C[j][l] tau_j (+ c_l tau_l on h0)
    float dot_p = Ca.x*ta.x + Ca.y*ta.y + Ca.z*ta.z + Ca.w*ta.w
                + Cb.x*tb4.x + Cb.y*tb4.y + Cb.z*tb4.z + Cb.w*tb4.w;
    costacc += (double)( taul*0.5f*dot_p + (h==0 ? taul*rc : 0.f) );

    if (h==0){
      if (l<12) out[(size_t)t*BB*12 + (size_t)b*12 + l] = xj;
      else      out[(size_t)TT*BB*12 + (size_t)t*BB*4 + (size_t)b*4 + (l-12)] = tauj;
    }

    if (t<TT-1 && h==0 && l<12){
      const float4 t0=tp[0],t1=tp[1],t2=tp[2],t3=tp[3];
      xj = rf
         + F0.x*t0.x+F0.y*t0.y+F0.z*t0.z+F0.w*t0.w
         + F1.x*t1.x+F1.y*t1.y+F1.z*t1.z+F1.w*t1.w
         + F2.x*t2.x+F2.y*t2.y+F2.z*t2.z+F2.w*t2.w
         + F3.x*t3.x+F3.y*t3.y+F3.z*t3.z+F3.w*t3.w;
    }
    // tau WAR across iters: ping-pong buffer
  }

  costacc+=__shfl_xor(costacc,1,64); costacc+=__shfl_xor(costacc,2,64);
  costacc+=__shfl_xor(costacc,4,64); costacc+=__shfl_xor(costacc,8,64);
  costacc+=__shfl_xor(costacc,32,64);   // h-halves are lane^32 now
  if (h==0 && l==0) out[(size_t)TT*BB*16 + b]=(float)costacc;
}

extern "C" void kernel_launch(void* const* d_in, const int* in_sizes, int n_in,
                              void* d_out, int out_size, void* d_ws, size_t ws_size,
                              hipStream_t stream){
  (void)in_sizes; (void)n_in; (void)out_size;
  const float* xinit=(const float*)d_in[0];
  const float* C    =(const float*)d_in[1];
  const float* c    =(const float*)d_in[2];
  const float* F    =(const float*)d_in[3];
  const float* f    =(const float*)d_in[4];
  const size_t need_f32 = (size_t)TT*BB*52*sizeof(float);   // 85.2 MB
  if (ws_size >= need_f32){
    lqr_fused<0><<<dim3(BB/8), dim3(256), 0, stream>>>(xinit,C,c,F,f,(float*)d_out,d_ws);
  } else {
    lqr_fused<1><<<dim3(BB/8), dim3(256), 0, stream>>>(xinit,C,c,F,f,(float*)d_out,d_ws);
  }
}